// Round 16
// baseline (156.780 us; speedup 1.0000x reference)
//
#include <hip/hip_runtime.h>
#include <hip/hip_bf16.h>

#define IN_DIM 128
#define HEADS 4
#define HID 16
#define HD 64   // HEADS*HID
#define NEG_SLOPE 0.2f
#define PSHIFT 7          // partition = dst >> 7 (128 nodes per partition)
#define PCAP 5120         // slots per partition region; mean 4096, +16 sigma pad
#define NPMAX 512
#define EPB 8192          // edges per block in partition role (196 blocks)
#define NB_PROJ 256       // projection-role blocks
#define NTILE 5           // 4 feat col-tiles + 1 el/er tile

typedef __attribute__((ext_vector_type(8))) short bf16x8;
typedef __attribute__((ext_vector_type(4))) float f32x4;

__device__ __forceinline__ float lrelu_exp(float x) {
    float e = x > 0.0f ? x : NEG_SLOPE * x;
    return __expf(e);
}

// fp32 -> bf16 round-to-nearest-even, as raw bits
__device__ __forceinline__ unsigned short f2bf(float x) {
    unsigned int u = __float_as_uint(x);
    return (unsigned short)((u + 0x7fffu + ((u >> 16) & 1u)) >> 16);
}

// ---------------------------------------------------------------------------
// Fused kernel 1: blocks [0, npartblk) scatter edges into padded per-partition
// regions; blocks [npartblk, +NB_PROJ) do the MFMA projection (W staged in
// LDS in final B-fragment layout; 5th B-tile = premultiplied el/er columns;
// 1-deep cross-group A-tile prefetch).
// ---------------------------------------------------------------------------
__global__ __launch_bounds__(256) void k_prjpart(const float* __restrict__ features,
                                                 const float* __restrict__ W,
                                                 const float* __restrict__ attn_l,
                                                 const float* __restrict__ attn_r,
                                                 __hip_bfloat16* __restrict__ feat16,
                                                 float* __restrict__ el,
                                                 float* __restrict__ er,
                                                 const int* __restrict__ src,
                                                 const int* __restrict__ dst,
                                                 int* __restrict__ cursor,
                                                 unsigned int* __restrict__ partbuf,
                                                 int n_nodes, int n_edges,
                                                 int npart, int npartblk) {
    __shared__ float smem[IN_DIM * HD];  // 32 KB (union of all roles/phases)

    if (blockIdx.x < (unsigned)npartblk) {
        // ================= partition role (EPB=8192 edges/block) =========
        int* hist = (int*)smem;
        int* base = (int*)smem + NPMAX;
        const int t = threadIdx.x;
        for (int i = t; i < npart; i += 256) hist[i] = 0;
        __syncthreads();

        const int e0 = blockIdx.x * EPB;
        unsigned int vals[32];
#pragma unroll
        for (int j = 0; j < 8; ++j) {
            int e = e0 + j * 1024 + t * 4;
            if (e + 4 <= n_edges) {
                int4 s4 = *reinterpret_cast<const int4*>(src + e);
                int4 d4 = *reinterpret_cast<const int4*>(dst + e);
                vals[j * 4 + 0] = ((unsigned)d4.x << 16) | (unsigned)s4.x;
                vals[j * 4 + 1] = ((unsigned)d4.y << 16) | (unsigned)s4.y;
                vals[j * 4 + 2] = ((unsigned)d4.z << 16) | (unsigned)s4.z;
                vals[j * 4 + 3] = ((unsigned)d4.w << 16) | (unsigned)s4.w;
            } else {
#pragma unroll
                for (int k = 0; k < 4; ++k) {
                    int ee = e + k;
                    vals[j * 4 + k] = (ee < n_edges)
                        ? (((unsigned)dst[ee] << 16) | (unsigned)src[ee])
                        : 0xffffffffu;
                }
            }
        }
#pragma unroll
        for (int j = 0; j < 32; ++j)
            if (vals[j] != 0xffffffffu) atomicAdd(&hist[vals[j] >> (16 + PSHIFT)], 1);
        __syncthreads();
        for (int i = t; i < npart; i += 256) {
            base[i] = atomicAdd(&cursor[i], hist[i]);
            hist[i] = 0;
        }
        __syncthreads();
#pragma unroll
        for (int j = 0; j < 32; ++j) {
            unsigned int v = vals[j];
            if (v != 0xffffffffu) {
                int p = v >> (16 + PSHIFT);
                int idx = base[p] + atomicAdd(&hist[p], 1);
                if (idx < PCAP) partbuf[(size_t)p * PCAP + idx] = v;
            }
        }
        return;
    }

    // ================= projection role =================
    for (int i = threadIdx.x; i < IN_DIM * HD; i += 256) smem[i] = W[i];
    __syncthreads();

    uint4 ent[NTILE];
#pragma unroll
    for (int i = 0; i < NTILE; ++i) {
        const int e  = threadIdx.x + (i << 8);
        const int fi = e >> 6;
        const int ln = e & 63;
        const int c  = fi >> 2;
        const int q  = fi & 3;
        const int colid = ln & 15;
        const int quad  = ln >> 4;
        unsigned short v[8];
        if (c < 4) {
#pragma unroll
            for (int j = 0; j < 8; ++j) {
                int k = q * 32 + quad * 8 + j;
                v[j] = f2bf(smem[k * HD + c * 16 + colid]);
            }
        } else if (colid < 8) {
            const int h = colid & 3;
            const float* attn = (colid < 4) ? attn_l : attn_r;
            float at[16];
#pragma unroll
            for (int d = 0; d < 16; ++d) at[d] = attn[h * 16 + d];
#pragma unroll
            for (int j = 0; j < 8; ++j) {
                int k = q * 32 + quad * 8 + j;
                float sum = 0.f;
#pragma unroll
                for (int d = 0; d < 16; ++d)
                    sum = fmaf(smem[k * HD + h * 16 + d], at[d], sum);
                v[j] = f2bf(sum);
            }
        } else {
#pragma unroll
            for (int j = 0; j < 8; ++j) v[j] = 0;
        }
        ent[i].x = (unsigned int)v[0] | ((unsigned int)v[1] << 16);
        ent[i].y = (unsigned int)v[2] | ((unsigned int)v[3] << 16);
        ent[i].z = (unsigned int)v[4] | ((unsigned int)v[5] << 16);
        ent[i].w = (unsigned int)v[6] | ((unsigned int)v[7] << 16);
    }
    __syncthreads();

    uint4* fragw = (uint4*)smem;
#pragma unroll
    for (int i = 0; i < NTILE; ++i)
        fragw[threadIdx.x + (i << 8)] = ent[i];
    __syncthreads();

    const bf16x8* frags = (const bf16x8*)smem;
    const int lane  = threadIdx.x & 63;
    const int wave  = threadIdx.x >> 6;
    const int colid = lane & 15;
    const int quad  = lane >> 4;

    const int ngroups = (n_nodes + 15) >> 4;
    const int gwave = (blockIdx.x - npartblk) * 4 + wave;
    const int nwaves = NB_PROJ * 4;

    int g = gwave;
    float4 ra[8];
    if (g < ngroups) {
        int rown = g * 16 + colid;
        if (rown >= n_nodes) rown = n_nodes - 1;
        const float* fp = features + (size_t)rown * IN_DIM + quad * 8;
#pragma unroll
        for (int q = 0; q < 4; ++q) {
            ra[q * 2]     = *reinterpret_cast<const float4*>(fp + q * 32);
            ra[q * 2 + 1] = *reinterpret_cast<const float4*>(fp + q * 32 + 4);
        }
    }

    while (g < ngroups) {
        const int gn = g + nwaves;
        float4 rb[8];
        if (gn < ngroups) {
            int rown = gn * 16 + colid;
            if (rown >= n_nodes) rown = n_nodes - 1;
            const float* fp = features + (size_t)rown * IN_DIM + quad * 8;
#pragma unroll
            for (int q = 0; q < 4; ++q) {
                rb[q * 2]     = *reinterpret_cast<const float4*>(fp + q * 32);
                rb[q * 2 + 1] = *reinterpret_cast<const float4*>(fp + q * 32 + 4);
            }
        }

        const int n0 = g * 16;
        f32x4 acc[NTILE];
#pragma unroll
        for (int c = 0; c < NTILE; ++c) acc[c] = (f32x4){0.f, 0.f, 0.f, 0.f};

#pragma unroll
        for (int q = 0; q < 4; ++q) {
            float4 a0 = ra[q * 2];
            float4 a1 = ra[q * 2 + 1];
            bf16x8 av;
            av[0] = (short)f2bf(a0.x); av[1] = (short)f2bf(a0.y);
            av[2] = (short)f2bf(a0.z); av[3] = (short)f2bf(a0.w);
            av[4] = (short)f2bf(a1.x); av[5] = (short)f2bf(a1.y);
            av[6] = (short)f2bf(a1.z); av[7] = (short)f2bf(a1.w);
#pragma unroll
            for (int c = 0; c < NTILE; ++c) {
                bf16x8 bv = frags[(c * 4 + q) * 64 + lane];  // ds_read_b128
                acc[c] = __builtin_amdgcn_mfma_f32_16x16x32_bf16(av, bv, acc[c], 0, 0, 0);
            }
        }

        const bool full = (n0 + 16 <= n_nodes);
#pragma unroll
        for (int c = 0; c < 4; ++c) {
#pragma unroll
            for (int r = 0; r < 4; ++r) {
                int n = n0 + quad * 4 + r;
                if (full || n < n_nodes) {
                    ((unsigned short*)feat16)[(size_t)n * HD + c * 16 + colid] = f2bf(acc[c][r]);
                }
            }
        }
        if (colid < 8) {
            float* dstp = (colid < 4) ? el : er;
            const int h = colid & 3;
#pragma unroll
            for (int r = 0; r < 4; ++r) {
                int n = n0 + quad * 4 + r;
                if (full || n < n_nodes) {
                    dstp[(size_t)n * HEADS + h] = acc[4][r];
                }
            }
        }

#pragma unroll
        for (int j = 0; j < 8; ++j) ra[j] = rb[j];
        g = gn;
    }
}

// ---------------------------------------------------------------------------
// Fused kernel 2: per-partition counting sort (CSR into LDS) + softmax +
// aggregation. One block per partition (512 threads = 8 waves); each wave
// then processes 16 of the partition's 128 nodes with the pipelined
// per-node loop, reading edge lists from LDS instead of global CSR.
// ---------------------------------------------------------------------------
__global__ __launch_bounds__(512) void k_sortagg(const unsigned int* __restrict__ partbuf,
                                                 const int* __restrict__ cursor,
                                                 const float* __restrict__ el,
                                                 const float* __restrict__ er,
                                                 const unsigned int* __restrict__ feat16u,
                                                 const float* __restrict__ bias,
                                                 float* __restrict__ out,
                                                 int n_nodes) {
    __shared__ unsigned short csr_l[PCAP];   // 10 KB
    __shared__ int hist[128];
    __shared__ int rowbeg[128];
    __shared__ int rowdeg[128];

    const int p = blockIdx.x;
    const int t = threadIdx.x;
    const int count = min(cursor[p], PCAP);
    const unsigned int* buf = partbuf + (size_t)p * PCAP;

    // ---- phase 1: counting sort into LDS ----
    unsigned int vals[10];
#pragma unroll
    for (int j = 0; j < 10; ++j) {
        int i = t + j * 512;
        vals[j] = (i < count) ? buf[i] : 0xffffffffu;
    }

    if (t < 128) hist[t] = 0;
    __syncthreads();
#pragma unroll
    for (int j = 0; j < 10; ++j)
        if (vals[j] != 0xffffffffu) atomicAdd(&hist[(vals[j] >> 16) & 127], 1);
    __syncthreads();

    int v = 0;
    if (t < 128) {
        v = hist[t];
        rowbeg[t] = v;   // temp: counts; scanned below
    }
    __syncthreads();
    // Hillis-Steele scan over 128 (t<128 active)
    for (int off = 1; off < 128; off <<= 1) {
        int u = (t >= off && t < 128) ? rowbeg[t - off] : 0;
        __syncthreads();
        if (t < 128) rowbeg[t] += u;
        __syncthreads();
    }
    if (t < 128) {
        const int excl = rowbeg[t] - v;
        rowbeg[t] = excl;
        rowdeg[t] = v;
        hist[t] = excl;   // rank cursor for the scatter
    }
    __syncthreads();
#pragma unroll
    for (int j = 0; j < 10; ++j) {
        unsigned int val = vals[j];
        if (val != 0xffffffffu) {
            int ld = (val >> 16) & 127;
            int pos = atomicAdd(&hist[ld], 1);
            csr_l[pos] = (unsigned short)(val & 0xffffu);
        }
    }
    __syncthreads();

    // ---- phase 2: per-node softmax + aggregation (wave per node-slice) ----
    const int wave = t >> 6;
    const int lane = t & 63;
    const int half = lane >> 5;
    const int sub = lane & 31;        // h*8 + dp
    const int h = sub >> 3;
    const int eW = lane >> 2;         // 0..15
    const int hW = lane & 3;
    const int baseLane = half * 4 + h;

    for (int i = 0; i < 16; ++i) {
        const int ln = wave * 16 + i;            // local node in partition
        const int n = (p << PSHIFT) + ln;
        if (n >= n_nodes) break;                 // only last partition partial

        const int beg = rowbeg[ln];
        const int deg = rowdeg[ln];
        const float erW = er[(size_t)n * HEADS + hW];

        float nx0 = 0.f, ny0 = 0.f, nx1 = 0.f, ny1 = 0.f;
        float denacc = 0.f;

        bool valid = (eW < deg);
        int s = valid ? (int)csr_l[beg + eW] : 0;
        float w = valid ? lrelu_exp(el[(size_t)s * HEADS + hW] + erW) : 0.f;

        for (int i0 = 0; i0 < deg; i0 += 16) {
            denacc += w;
            const unsigned int pw = ((unsigned int)f2bf(w) << 16) | (unsigned int)s;

            unsigned int pk[8];
#pragma unroll
            for (int j = 0; j < 8; ++j) pk[j] = __shfl(pw, baseLane + (j << 3));

            const bool v2 = (i0 + 16 + eW < deg);
            int s2 = v2 ? (int)csr_l[beg + i0 + 16 + eW] : 0;

            unsigned int pf[8];
#pragma unroll
            for (int j = 0; j < 8; ++j)
                pf[j] = feat16u[((pk[j] & 0xffffu) << 5) + sub];

            float w2 = v2 ? lrelu_exp(el[(size_t)s2 * HEADS + hW] + erW) : 0.f;

#pragma unroll
            for (int j = 0; j < 8; ++j) {
                float wj = __uint_as_float(pk[j] & 0xffff0000u);   // bf16 w
                if (j & 1) {
                    nx1 = fmaf(wj, __uint_as_float(pf[j] << 16), nx1);
                    ny1 = fmaf(wj, __uint_as_float(pf[j] & 0xffff0000u), ny1);
                } else {
                    nx0 = fmaf(wj, __uint_as_float(pf[j] << 16), nx0);
                    ny0 = fmaf(wj, __uint_as_float(pf[j] & 0xffff0000u), ny0);
                }
            }
            s = s2;
            w = w2;
        }

        float den = denacc;
        den += __shfl_xor(den, 4);
        den += __shfl_xor(den, 8);
        den += __shfl_xor(den, 16);
        den += __shfl_xor(den, 32);
        float denh = __shfl(den, h);

        float nx = nx0 + nx1, ny = ny0 + ny1;
        nx += __shfl_xor(nx, 32);
        ny += __shfl_xor(ny, 32);
        float inv = (denh > 0.f) ? 0.25f / denh : 0.f;   // 0.25 = head mean
        float rx = nx * inv;
        float ry = ny * inv;
        rx += __shfl_xor(rx, 8);
        ry += __shfl_xor(ry, 8);
        rx += __shfl_xor(rx, 16);
        ry += __shfl_xor(ry, 16);
        if (lane < 8) {
            int dp = lane;
            float bx = 0.25f * (bias[2 * dp] + bias[HID + 2 * dp] +
                                bias[2 * HID + 2 * dp] + bias[3 * HID + 2 * dp]);
            float by = 0.25f * (bias[2 * dp + 1] + bias[HID + 2 * dp + 1] +
                                bias[2 * HID + 2 * dp + 1] + bias[3 * HID + 2 * dp + 1]);
            *reinterpret_cast<float2*>(out + (size_t)n * HID + 2 * dp) =
                make_float2(rx + bx, ry + by);
        }
    }
}

// ---------------------------------------------------------------------------
extern "C" void kernel_launch(void* const* d_in, const int* in_sizes, int n_in,
                              void* d_out, int out_size, void* d_ws, size_t ws_size,
                              hipStream_t stream) {
    const float* features = (const float*)d_in[0];
    const float* W        = (const float*)d_in[1];
    const float* attn_l   = (const float*)d_in[2];
    const float* attn_r   = (const float*)d_in[3];
    const float* bias     = (const float*)d_in[4];
    const int*   src      = (const int*)d_in[5];
    const int*   dst      = (const int*)d_in[6];
    float* out = (float*)d_out;

    const int n_nodes = in_sizes[0] / IN_DIM;
    const int n_edges = in_sizes[5];
    const int npart = (n_nodes + (1 << PSHIFT) - 1) >> PSHIFT;   // 391 for 50000
    const int npartblk = (n_edges + EPB - 1) / EPB;              // 196

    // workspace layout (~14.7 MB)
    char* ws = (char*)d_ws;
    __hip_bfloat16* feat16 = (__hip_bfloat16*)ws; ws += (size_t)n_nodes * HD * sizeof(__hip_bfloat16);
    float* el      = (float*)ws;                  ws += (size_t)n_nodes * HEADS * sizeof(float);
    float* er      = (float*)ws;                  ws += (size_t)n_nodes * HEADS * sizeof(float);
    unsigned int* partbuf = (unsigned int*)ws;    ws += (size_t)npart * PCAP * sizeof(unsigned int);
    int* cursor    = (int*)ws;                    ws += NPMAX * sizeof(int);

    hipMemsetAsync(cursor, 0, NPMAX * sizeof(int), stream);

    // Fused: edge partition CONCURRENT with MFMA projection
    k_prjpart<<<npartblk + NB_PROJ, 256, 0, stream>>>(features, W, attn_l, attn_r,
                                                      feat16, el, er, src, dst,
                                                      cursor, partbuf,
                                                      n_nodes, n_edges, npart, npartblk);
    // Fused: per-partition LDS counting sort + softmax + aggregation
    k_sortagg<<<npart, 512, 0, stream>>>(partbuf, cursor, el, er,
                                         (const unsigned int*)feat16, bias, out, n_nodes);
}

// Round 17
// 151.370 us; speedup vs baseline: 1.0357x; 1.0357x over previous
//
#include <hip/hip_runtime.h>
#include <hip/hip_bf16.h>

#define IN_DIM 128
#define HEADS 4
#define HID 16
#define HD 64   // HEADS*HID
#define NEG_SLOPE 0.2f
#define PSHIFT 7          // partition = dst >> 7 (128 nodes per partition)
#define PCAP 5120         // slots per partition region; mean 4096, +16 sigma pad
#define NPMAX 512
#define EPB 8192          // edges per block in partition role (196 blocks)
#define NB_PROJ 256       // projection-role blocks
#define NTILE 5           // 4 feat col-tiles + 1 el/er tile

typedef __attribute__((ext_vector_type(8))) short bf16x8;
typedef __attribute__((ext_vector_type(4))) float f32x4;

__device__ __forceinline__ float lrelu_exp(float x) {
    float e = x > 0.0f ? x : NEG_SLOPE * x;
    return __expf(e);
}

// fp32 -> bf16 round-to-nearest-even, as raw bits
__device__ __forceinline__ unsigned short f2bf(float x) {
    unsigned int u = __float_as_uint(x);
    return (unsigned short)((u + 0x7fffu + ((u >> 16) & 1u)) >> 16);
}

// ---------------------------------------------------------------------------
// Fused kernel: blocks [0, npartblk) scatter edges into padded per-partition
// regions; blocks [npartblk, +NB_PROJ) do the MFMA projection.
// W staged in LDS in final B-fragment bf16 layout (conflict-free b128 reads);
// 5th B-tile = premultiplied el/er columns (el/er fall out of the MFMA).
// ---------------------------------------------------------------------------
__global__ __launch_bounds__(256) void k_prjpart(const float* __restrict__ features,
                                                 const float* __restrict__ W,
                                                 const float* __restrict__ attn_l,
                                                 const float* __restrict__ attn_r,
                                                 __hip_bfloat16* __restrict__ feat16,
                                                 float* __restrict__ el,
                                                 float* __restrict__ er,
                                                 const int* __restrict__ src,
                                                 const int* __restrict__ dst,
                                                 int* __restrict__ cursor,
                                                 unsigned int* __restrict__ partbuf,
                                                 int n_nodes, int n_edges,
                                                 int npart, int npartblk) {
    __shared__ float smem[IN_DIM * HD];  // 32 KB (union of all roles/phases)

    if (blockIdx.x < (unsigned)npartblk) {
        // ================= partition role (EPB=8192 edges/block) =========
        int* hist = (int*)smem;
        int* base = (int*)smem + NPMAX;
        const int t = threadIdx.x;
        for (int i = t; i < npart; i += 256) hist[i] = 0;
        __syncthreads();

        const int e0 = blockIdx.x * EPB;
        unsigned int vals[32];
#pragma unroll
        for (int j = 0; j < 8; ++j) {
            int e = e0 + j * 1024 + t * 4;
            if (e + 4 <= n_edges) {
                int4 s4 = *reinterpret_cast<const int4*>(src + e);
                int4 d4 = *reinterpret_cast<const int4*>(dst + e);
                vals[j * 4 + 0] = ((unsigned)d4.x << 16) | (unsigned)s4.x;
                vals[j * 4 + 1] = ((unsigned)d4.y << 16) | (unsigned)s4.y;
                vals[j * 4 + 2] = ((unsigned)d4.z << 16) | (unsigned)s4.z;
                vals[j * 4 + 3] = ((unsigned)d4.w << 16) | (unsigned)s4.w;
            } else {
#pragma unroll
                for (int k = 0; k < 4; ++k) {
                    int ee = e + k;
                    vals[j * 4 + k] = (ee < n_edges)
                        ? (((unsigned)dst[ee] << 16) | (unsigned)src[ee])
                        : 0xffffffffu;
                }
            }
        }
#pragma unroll
        for (int j = 0; j < 32; ++j)
            if (vals[j] != 0xffffffffu) atomicAdd(&hist[vals[j] >> (16 + PSHIFT)], 1);
        __syncthreads();
        for (int i = t; i < npart; i += 256) {
            base[i] = atomicAdd(&cursor[i], hist[i]);
            hist[i] = 0;
        }
        __syncthreads();
#pragma unroll
        for (int j = 0; j < 32; ++j) {
            unsigned int v = vals[j];
            if (v != 0xffffffffu) {
                int p = v >> (16 + PSHIFT);
                int idx = base[p] + atomicAdd(&hist[p], 1);
                if (idx < PCAP) partbuf[(size_t)p * PCAP + idx] = v;
            }
        }
        return;
    }

    // ================= projection role =================
    for (int i = threadIdx.x; i < IN_DIM * HD; i += 256) smem[i] = W[i];
    __syncthreads();

    uint4 ent[NTILE];
#pragma unroll
    for (int i = 0; i < NTILE; ++i) {
        const int e  = threadIdx.x + (i << 8);
        const int fi = e >> 6;
        const int ln = e & 63;
        const int c  = fi >> 2;
        const int q  = fi & 3;
        const int colid = ln & 15;
        const int quad  = ln >> 4;
        unsigned short v[8];
        if (c < 4) {
#pragma unroll
            for (int j = 0; j < 8; ++j) {
                int k = q * 32 + quad * 8 + j;
                v[j] = f2bf(smem[k * HD + c * 16 + colid]);
            }
        } else if (colid < 8) {
            const int h = colid & 3;
            const float* attn = (colid < 4) ? attn_l : attn_r;
            float at[16];
#pragma unroll
            for (int d = 0; d < 16; ++d) at[d] = attn[h * 16 + d];
#pragma unroll
            for (int j = 0; j < 8; ++j) {
                int k = q * 32 + quad * 8 + j;
                float sum = 0.f;
#pragma unroll
                for (int d = 0; d < 16; ++d)
                    sum = fmaf(smem[k * HD + h * 16 + d], at[d], sum);
                v[j] = f2bf(sum);
            }
        } else {
#pragma unroll
            for (int j = 0; j < 8; ++j) v[j] = 0;
        }
        ent[i].x = (unsigned int)v[0] | ((unsigned int)v[1] << 16);
        ent[i].y = (unsigned int)v[2] | ((unsigned int)v[3] << 16);
        ent[i].z = (unsigned int)v[4] | ((unsigned int)v[5] << 16);
        ent[i].w = (unsigned int)v[6] | ((unsigned int)v[7] << 16);
    }
    __syncthreads();

    uint4* fragw = (uint4*)smem;
#pragma unroll
    for (int i = 0; i < NTILE; ++i)
        fragw[threadIdx.x + (i << 8)] = ent[i];
    __syncthreads();

    const bf16x8* frags = (const bf16x8*)smem;
    const int lane  = threadIdx.x & 63;
    const int wave  = threadIdx.x >> 6;
    const int colid = lane & 15;
    const int quad  = lane >> 4;

    const int ngroups = (n_nodes + 15) >> 4;
    const int gwave = (blockIdx.x - npartblk) * 4 + wave;
    const int nwaves = NB_PROJ * 4;

    int g = gwave;
    float4 ra[8];
    if (g < ngroups) {
        int rown = g * 16 + colid;
        if (rown >= n_nodes) rown = n_nodes - 1;
        const float* fp = features + (size_t)rown * IN_DIM + quad * 8;
#pragma unroll
        for (int q = 0; q < 4; ++q) {
            ra[q * 2]     = *reinterpret_cast<const float4*>(fp + q * 32);
            ra[q * 2 + 1] = *reinterpret_cast<const float4*>(fp + q * 32 + 4);
        }
    }

    while (g < ngroups) {
        const int gn = g + nwaves;
        float4 rb[8];
        if (gn < ngroups) {
            int rown = gn * 16 + colid;
            if (rown >= n_nodes) rown = n_nodes - 1;
            const float* fp = features + (size_t)rown * IN_DIM + quad * 8;
#pragma unroll
            for (int q = 0; q < 4; ++q) {
                rb[q * 2]     = *reinterpret_cast<const float4*>(fp + q * 32);
                rb[q * 2 + 1] = *reinterpret_cast<const float4*>(fp + q * 32 + 4);
            }
        }

        const int n0 = g * 16;
        f32x4 acc[NTILE];
#pragma unroll
        for (int c = 0; c < NTILE; ++c) acc[c] = (f32x4){0.f, 0.f, 0.f, 0.f};

#pragma unroll
        for (int q = 0; q < 4; ++q) {
            float4 a0 = ra[q * 2];
            float4 a1 = ra[q * 2 + 1];
            bf16x8 av;
            av[0] = (short)f2bf(a0.x); av[1] = (short)f2bf(a0.y);
            av[2] = (short)f2bf(a0.z); av[3] = (short)f2bf(a0.w);
            av[4] = (short)f2bf(a1.x); av[5] = (short)f2bf(a1.y);
            av[6] = (short)f2bf(a1.z); av[7] = (short)f2bf(a1.w);
#pragma unroll
            for (int c = 0; c < NTILE; ++c) {
                bf16x8 bv = frags[(c * 4 + q) * 64 + lane];  // ds_read_b128
                acc[c] = __builtin_amdgcn_mfma_f32_16x16x32_bf16(av, bv, acc[c], 0, 0, 0);
            }
        }

        const bool full = (n0 + 16 <= n_nodes);
#pragma unroll
        for (int c = 0; c < 4; ++c) {
#pragma unroll
            for (int r = 0; r < 4; ++r) {
                int n = n0 + quad * 4 + r;
                if (full || n < n_nodes) {
                    ((unsigned short*)feat16)[(size_t)n * HD + c * 16 + colid] = f2bf(acc[c][r]);
                }
            }
        }
        if (colid < 8) {
            float* dstp = (colid < 4) ? el : er;
            const int h = colid & 3;
#pragma unroll
            for (int r = 0; r < 4; ++r) {
                int n = n0 + quad * 4 + r;
                if (full || n < n_nodes) {
                    dstp[(size_t)n * HEADS + h] = acc[4][r];
                }
            }
        }

#pragma unroll
        for (int j = 0; j < 8; ++j) ra[j] = rb[j];
        g = gn;
    }
}

// ---------------------------------------------------------------------------
// Per-partition counting sort, single pass over partbuf.
// ---------------------------------------------------------------------------
__global__ __launch_bounds__(512) void k_sort(const unsigned int* __restrict__ partbuf,
                                              const int* __restrict__ cursor,
                                              unsigned short* __restrict__ csr,
                                              int* __restrict__ row_ptr,
                                              unsigned short* __restrict__ deg16,
                                              int n_nodes) {
    __shared__ int hist[128];
    __shared__ int scan_s[128];
    const int p = blockIdx.x;
    const int t = threadIdx.x;
    const int count = min(cursor[p], PCAP);
    const unsigned int* buf = partbuf + (size_t)p * PCAP;

    unsigned int vals[10];
#pragma unroll
    for (int j = 0; j < 10; ++j) {
        int i = t + j * 512;
        vals[j] = (i < count) ? buf[i] : 0xffffffffu;
    }

    if (t < 128) hist[t] = 0;
    __syncthreads();
#pragma unroll
    for (int j = 0; j < 10; ++j)
        if (vals[j] != 0xffffffffu) atomicAdd(&hist[(vals[j] >> 16) & 127], 1);
    __syncthreads();

    int v = 0;
    if (t < 128) {
        v = hist[t];
        scan_s[t] = v;
    }
    __syncthreads();
    for (int off = 1; off < 128; off <<= 1) {
        int u = (t >= off && t < 128) ? scan_s[t - off] : 0;
        __syncthreads();
        if (t < 128) scan_s[t] += u;
        __syncthreads();
    }
    if (t < 128) {
        const int excl = scan_s[t] - v;
        const int node = (p << PSHIFT) + t;
        if (node < n_nodes) {
            row_ptr[node] = p * PCAP + excl;
            deg16[node] = (unsigned short)v;
        }
        hist[t] = excl;   // reuse as rank cursor
    }
    __syncthreads();
    unsigned short* cbase = csr + (size_t)p * PCAP;
#pragma unroll
    for (int j = 0; j < 10; ++j) {
        unsigned int val = vals[j];
        if (val != 0xffffffffu) {
            int ld = (val >> 16) & 127;
            int pos = atomicAdd(&hist[ld], 1);
            cbase[pos] = (unsigned short)(val & 0xffffu);
        }
    }
}

// ---------------------------------------------------------------------------
// Fused softmax + aggregation, software-pipelined (round-12 shape).
// ---------------------------------------------------------------------------
__global__ __launch_bounds__(256) void k_agg(const int* __restrict__ row_ptr,
                                             const unsigned short* __restrict__ deg16,
                                             const unsigned short* __restrict__ csr,
                                             const float* __restrict__ el,
                                             const float* __restrict__ er,
                                             const unsigned int* __restrict__ feat16u,
                                             const float* __restrict__ bias,
                                             float* __restrict__ out,
                                             int n_nodes) {
    int n = (blockIdx.x * blockDim.x + threadIdx.x) >> 6;
    if (n >= n_nodes) return;
    const int lane = threadIdx.x & 63;
    const int half = lane >> 5;
    const int sub = lane & 31;        // h*8 + dp
    const int h = sub >> 3;
    const int eW = lane >> 2;         // 0..15
    const int hW = lane & 3;

    const int beg = row_ptr[n];
    const int deg = (int)deg16[n];
    const unsigned short* row = csr + beg;
    const float erW = er[(size_t)n * HEADS + hW];

    const int baseLane = half * 4 + h;

    float nx0 = 0.f, ny0 = 0.f, nx1 = 0.f, ny1 = 0.f;
    float denacc = 0.f;

    bool valid = (eW < deg);
    int s = valid ? (int)row[eW] : 0;
    float w = valid ? lrelu_exp(el[(size_t)s * HEADS + hW] + erW) : 0.f;

    for (int i0 = 0; i0 < deg; i0 += 16) {
        denacc += w;
        const unsigned int pw = ((unsigned int)f2bf(w) << 16) | (unsigned int)s;

        unsigned int pk[8];
#pragma unroll
        for (int j = 0; j < 8; ++j) pk[j] = __shfl(pw, baseLane + (j << 3));

        const bool v2 = (i0 + 16 + eW < deg);
        int s2 = v2 ? (int)row[i0 + 16 + eW] : 0;

        unsigned int pf[8];
#pragma unroll
        for (int j = 0; j < 8; ++j)
            pf[j] = feat16u[((pk[j] & 0xffffu) << 5) + sub];

        float w2 = v2 ? lrelu_exp(el[(size_t)s2 * HEADS + hW] + erW) : 0.f;

#pragma unroll
        for (int j = 0; j < 8; ++j) {
            float wj = __uint_as_float(pk[j] & 0xffff0000u);   // bf16 w (0 for pad)
            if (j & 1) {
                nx1 = fmaf(wj, __uint_as_float(pf[j] << 16), nx1);
                ny1 = fmaf(wj, __uint_as_float(pf[j] & 0xffff0000u), ny1);
            } else {
                nx0 = fmaf(wj, __uint_as_float(pf[j] << 16), nx0);
                ny0 = fmaf(wj, __uint_as_float(pf[j] & 0xffff0000u), ny0);
            }
        }
        s = s2;
        w = w2;
    }

    float den = denacc;
    den += __shfl_xor(den, 4);
    den += __shfl_xor(den, 8);
    den += __shfl_xor(den, 16);
    den += __shfl_xor(den, 32);
    float denh = __shfl(den, h);

    float nx = nx0 + nx1, ny = ny0 + ny1;
    nx += __shfl_xor(nx, 32);
    ny += __shfl_xor(ny, 32);
    float inv = (denh > 0.f) ? 0.25f / denh : 0.f;   // 0.25 = head mean
    float rx = nx * inv;
    float ry = ny * inv;
    rx += __shfl_xor(rx, 8);
    ry += __shfl_xor(ry, 8);
    rx += __shfl_xor(rx, 16);
    ry += __shfl_xor(ry, 16);
    if (lane < 8) {
        int dp = lane;
        float bx = 0.25f * (bias[2 * dp] + bias[HID + 2 * dp] +
                            bias[2 * HID + 2 * dp] + bias[3 * HID + 2 * dp]);
        float by = 0.25f * (bias[2 * dp + 1] + bias[HID + 2 * dp + 1] +
                            bias[2 * HID + 2 * dp + 1] + bias[3 * HID + 2 * dp + 1]);
        *reinterpret_cast<float2*>(out + (size_t)n * HID + 2 * dp) =
            make_float2(rx + bx, ry + by);
    }
}

// ---------------------------------------------------------------------------
extern "C" void kernel_launch(void* const* d_in, const int* in_sizes, int n_in,
                              void* d_out, int out_size, void* d_ws, size_t ws_size,
                              hipStream_t stream) {
    const float* features = (const float*)d_in[0];
    const float* W        = (const float*)d_in[1];
    const float* attn_l   = (const float*)d_in[2];
    const float* attn_r   = (const float*)d_in[3];
    const float* bias     = (const float*)d_in[4];
    const int*   src      = (const int*)d_in[5];
    const int*   dst      = (const int*)d_in[6];
    float* out = (float*)d_out;

    const int n_nodes = in_sizes[0] / IN_DIM;
    const int n_edges = in_sizes[5];
    const int npart = (n_nodes + (1 << PSHIFT) - 1) >> PSHIFT;   // 391 for 50000
    const int npartblk = (n_edges + EPB - 1) / EPB;              // 196

    // workspace layout (~19.6 MB)
    char* ws = (char*)d_ws;
    __hip_bfloat16* feat16 = (__hip_bfloat16*)ws; ws += (size_t)n_nodes * HD * sizeof(__hip_bfloat16);
    float* el      = (float*)ws;                  ws += (size_t)n_nodes * HEADS * sizeof(float);
    float* er      = (float*)ws;                  ws += (size_t)n_nodes * HEADS * sizeof(float);
    unsigned int* partbuf = (unsigned int*)ws;    ws += (size_t)npart * PCAP * sizeof(unsigned int);
    unsigned short* csr = (unsigned short*)ws;    ws += (size_t)npart * PCAP * sizeof(unsigned short);
    int* row_ptr   = (int*)ws;                    ws += (size_t)n_nodes * sizeof(int);
    unsigned short* deg16 = (unsigned short*)ws;  ws += (size_t)n_nodes * sizeof(unsigned short);
    int* cursor    = (int*)ws;                    ws += NPMAX * sizeof(int);

    hipMemsetAsync(cursor, 0, NPMAX * sizeof(int), stream);

    // Fused: edge partition CONCURRENT with MFMA projection
    k_prjpart<<<npartblk + NB_PROJ, 256, 0, stream>>>(features, W, attn_l, attn_r,
                                                      feat16, el, er, src, dst,
                                                      cursor, partbuf,
                                                      n_nodes, n_edges, npart, npartblk);
    // Per-partition counting sort (single pass)
    k_sort<<<npart, 512, 0, stream>>>(partbuf, cursor, csr, row_ptr, deg16, n_nodes);
    // Fused softmax + aggregation, one wave per node
    k_agg<<<(n_nodes + 3) / 4, 256, 0, stream>>>(row_ptr, deg16, csr, el, er,
                                                 (const unsigned int*)feat16, bias, out, n_nodes);
}